// Round 2
// baseline (1429.750 us; speedup 1.0000x reference)
//
#include <hip/hip_runtime.h>
#include <stdint.h>

// bf16 MFMA fragment types per cdna_hip_programming.md §3
typedef __attribute__((ext_vector_type(8))) short bf16x8;   // 8 bf16 = 4 VGPRs
typedef __attribute__((ext_vector_type(4))) float f32x4;    // C/D for 16x16x32

#define MFMA16(a, b, c) __builtin_amdgcn_mfma_f32_16x16x32_bf16((a), (b), (c), 0, 0, 0)

__device__ __forceinline__ unsigned short f2bf(float f) {
  unsigned int b = __float_as_uint(f);
  b += 0x7FFFu + ((b >> 16) & 1u);   // RNE
  return (unsigned short)(b >> 16);
}
// pack two float4 -> 8 bf16 (RNE)
__device__ __forceinline__ bf16x8 cvt8(const float4 a, const float4 b) {
  bf16x8 r;
  r[0] = (short)f2bf(a.x); r[1] = (short)f2bf(a.y);
  r[2] = (short)f2bf(a.z); r[3] = (short)f2bf(a.w);
  r[4] = (short)f2bf(b.x); r[5] = (short)f2bf(b.y);
  r[6] = (short)f2bf(b.z); r[7] = (short)f2bf(b.w);
  return r;
}
// weight fragment load: bf16 direct (16B) or fp32 + convert (fallback)
template <bool BF16W>
__device__ __forceinline__ bf16x8 ldw(const void* p, size_t off) {
  if constexpr (BF16W) {
    return *(const bf16x8*)((const unsigned short*)p + off);
  } else {
    const float* f = (const float*)p + off;
    return cvt8(*(const float4*)f, *(const float4*)(f + 4));
  }
}
// XOR-swizzled LDS tile index (pitch 512 elems, chunk = 8 elems = 16B).
__device__ __forceinline__ int sw(int row, int chunk) {
  return row * 512 + ((chunk ^ (row & 7)) << 3);
}

// ---------------------------------------------------------------------------
// K0: convert Wq,Wk,Wv,Wp (fp32, 262144 each) -> bf16 FRAGMENT-PACKED layout.
// Packed chunk index c (8 elems each): bits [14:10]=g, [9:6]=kk, [5:4]=quad,
// [3:0]=m. Content: W[g*16+m][kk*32+quad*8 .. +8].
//   K1 frag (head h, n-tile ni, k-step kx): g = h*2+ni  -> every wave load is
//     base + lane*16B, a fully coalesced 1KB read (was a 16-line 16KB-span
//     divergent read).
//   K2 frag (wave w, ni, kx): g = w*8+ni  (same formula).
// ---------------------------------------------------------------------------
__global__ void cvt_weights_k(const float* __restrict__ wq,
                              const float* __restrict__ wk,
                              const float* __restrict__ wv,
                              const float* __restrict__ wp,
                              unsigned short* __restrict__ dst) {
  const int seg = blockIdx.x >> 7;   // 0..3
  const int blk = blockIdx.x & 127;
  const float* src = (seg == 0) ? wq : (seg == 1) ? wk : (seg == 2) ? wv : wp;
  unsigned short* d = dst + (size_t)seg * 262144;
  const int c = blk * 256 + threadIdx.x;          // 0..32767
  const int row = ((c >> 10) << 4) + (c & 15);    // g*16 + m
  const int col = ((c >> 6) & 15) * 32 + ((c >> 4) & 3) * 8;  // kk*32 + quad*8
  const float* s = src + row * 512 + col;
  *(bf16x8*)&d[(size_t)c * 8] = cvt8(*(const float4*)s, *(const float4*)(s + 4));
}

// Weight fragment offset: packed (bf16 ws) vs original row-major (fp32 fallback).
// off(ni,kx) = base + ni*8192 + kx*kmul in both cases.
template <bool PACKED>
__device__ __forceinline__ size_t wbase0(int g32, int lane, int m, int quad) {
  // g32 = head*32 (K1) or wave*128 (K2) -- the first row of this wave's panel
  if constexpr (PACKED) return (size_t)g32 * 512 + (size_t)lane * 8;
  else                  return (size_t)(g32 + m) * 512 + quad * 8;
}

// ---------------------------------------------------------------------------
// K1: per-batch fused QKV projection + causal attention.
// R2: fragment-packed coalesced weight loads; deferred V-spill reuses K's
// scratch buffer -> LDS 52KB -> 3 blocks/CU (was 2). No koff/hgo stagger.
// grid = 4096 (one batch), block = 256 (4 waves; wave w -> head hg*4+w).
// ---------------------------------------------------------------------------
template <bool BF16W>
__global__ __launch_bounds__(256, 3) void qkv_attn_k(
    const float* __restrict__ x,
    const void* __restrict__ wq,
    const void* __restrict__ wk,
    const void* __restrict__ wv,
    float* __restrict__ y) {
  __shared__ __align__(16) unsigned short Xs[32 * 512];       // 32 KB bf16, swizzled
  __shared__ __align__(16) unsigned short Scr[4][2][32 * 40]; // per-wave Q/P + K/Vt, 20.5 KB
  const int tid  = threadIdx.x;
  const int lane = tid & 63;
  const int wave = tid >> 6;
  const int m    = lane & 15;   // tile row/col within 16
  const int quad = lane >> 4;   // 0..3
  const int b    = blockIdx.x;

  { // stage X[b] (32 x 512 fp32) into LDS as bf16
    const float* xg = x + (size_t)b * (32 * 512);
#pragma unroll
    for (int i = 0; i < 8; i++) {
      int c = tid + 256 * i;          // 2048 chunks of 8 elems
      int row = c >> 6, ch = c & 63;
      float4 lo = *(const float4*)&xg[row * 512 + ch * 8];
      float4 hi = *(const float4*)&xg[row * 512 + ch * 8 + 4];
      *(bf16x8*)&Xs[sw(row, ch)] = cvt8(lo, hi);
    }
  }
  __syncthreads();

  unsigned short* Qs = &Scr[wave][0][0];  // Q, later re-used for P
  unsigned short* Ks = &Scr[wave][1][0];  // K, later re-used for Vt

  for (int hg = 0; hg < 4; hg++) {
    const int h = hg * 4 + wave;
    // ---- GEMM: Q,K,V [32x32] = X[32x512] @ W_h[32x512]^T, fp32 acc
    f32x4 aq[2][2] = {}; f32x4 ak[2][2] = {}; f32x4 av[2][2] = {};
    const size_t wb = wbase0<BF16W>(h * 32, lane, m, quad);
    const int kmul = BF16W ? 512 : 32;

    bf16x8 a0A, a1A, bq0A, bq1A, bk0A, bk1A, bv0A, bv1A;
    bf16x8 a0B, a1B, bq0B, bq1B, bk0B, bk1B, bv0B, bv1B;

#define LDF(S, idx) { \
    const int kx = (idx); \
    const size_t kb = (size_t)kx * kmul; \
    a0##S  = *(const bf16x8*)&Xs[sw(m, kx * 4 + quad)]; \
    a1##S  = *(const bf16x8*)&Xs[sw(16 + m, kx * 4 + quad)]; \
    bq0##S = ldw<BF16W>(wq, wb + kb); \
    bq1##S = ldw<BF16W>(wq, wb + 8192 + kb); \
    bk0##S = ldw<BF16W>(wk, wb + kb); \
    bk1##S = ldw<BF16W>(wk, wb + 8192 + kb); \
    bv0##S = ldw<BF16W>(wv, wb + kb); \
    bv1##S = ldw<BF16W>(wv, wb + 8192 + kb); }

#define MMF(S) { \
    aq[0][0] = MFMA16(a0##S, bq0##S, aq[0][0]); \
    aq[1][0] = MFMA16(a1##S, bq0##S, aq[1][0]); \
    aq[0][1] = MFMA16(a0##S, bq1##S, aq[0][1]); \
    aq[1][1] = MFMA16(a1##S, bq1##S, aq[1][1]); \
    ak[0][0] = MFMA16(a0##S, bk0##S, ak[0][0]); \
    ak[1][0] = MFMA16(a1##S, bk0##S, ak[1][0]); \
    ak[0][1] = MFMA16(a0##S, bk1##S, ak[0][1]); \
    ak[1][1] = MFMA16(a1##S, bk1##S, ak[1][1]); \
    av[0][0] = MFMA16(a0##S, bv0##S, av[0][0]); \
    av[1][0] = MFMA16(a1##S, bv0##S, av[1][0]); \
    av[0][1] = MFMA16(a0##S, bv1##S, av[0][1]); \
    av[1][1] = MFMA16(a1##S, bv1##S, av[1][1]); }

    LDF(A, 0)
    for (int i = 0; i < 14; i += 2) {
      LDF(B, i + 1)
      MMF(A)
      LDF(A, i + 2)
      MMF(B)
    }
    LDF(B, 15)
    MMF(A)
    MMF(B)
#undef LDF
#undef MMF

    // ---- spill Q,K row-major (C-layout: row=quad*4+r, col=m); V stays in regs
#pragma unroll
    for (int mi = 0; mi < 2; mi++)
#pragma unroll
      for (int ni = 0; ni < 2; ni++)
#pragma unroll
        for (int r = 0; r < 4; r++) {
          int row = mi * 16 + quad * 4 + r;
          int col = ni * 16 + m;
          Qs[row * 40 + col] = f2bf(aq[mi][ni][r]);
          Ks[row * 40 + col] = f2bf(ak[mi][ni][r]);
        }
    // ---- S = Q K^T (K-dim = 32 -> single MFMA per 16x16 tile)
    f32x4 sAcc[2][2];
#pragma unroll
    for (int mi = 0; mi < 2; mi++)
#pragma unroll
      for (int ni = 0; ni < 2; ni++) {
        bf16x8 qa = *(const bf16x8*)&Qs[(mi * 16 + m) * 40 + quad * 8];
        bf16x8 kb = *(const bf16x8*)&Ks[(ni * 16 + m) * 40 + quad * 8];
        f32x4 z = {};
        sAcc[mi][ni] = MFMA16(qa, kb, z);
      }
    // ---- causal mask + softmax (row t lives in one 16-lane quad); P -> Qs
    float invs[2][4];
#pragma unroll
    for (int mi = 0; mi < 2; mi++)
#pragma unroll
      for (int r = 0; r < 4; r++) {
        int t = mi * 16 + quad * 4 + r;
        float s0 = sAcc[mi][0][r] * 0.17677669529663687f;  // 1/sqrt(32)
        float s1 = sAcc[mi][1][r] * 0.17677669529663687f;
        s0 = (m <= t) ? s0 : -1e30f;
        s1 = (16 + m <= t) ? s1 : -1e30f;
        float mx = fmaxf(s0, s1);
#pragma unroll
        for (int off = 1; off < 16; off <<= 1) mx = fmaxf(mx, __shfl_xor(mx, off));
        float e0 = __expf(s0 - mx);
        float e1 = __expf(s1 - mx);
        float sm = e0 + e1;
#pragma unroll
        for (int off = 1; off < 16; off <<= 1) sm += __shfl_xor(sm, off);
        invs[mi][r] = 1.0f / sm;           // normalize O after PV (fp32)
        Qs[t * 40 + m] = f2bf(e0);
        Qs[t * 40 + 16 + m] = f2bf(e1);
      }
    // ---- deferred V spill: K is dead after S-phase, reuse Ks as Vt[d][s]
#pragma unroll
    for (int mi = 0; mi < 2; mi++)
#pragma unroll
      for (int ni = 0; ni < 2; ni++)
#pragma unroll
        for (int r = 0; r < 4; r++) {
          int row = mi * 16 + quad * 4 + r;
          int col = ni * 16 + m;
          Ks[col * 40 + row] = f2bf(av[mi][ni][r]);
        }
    // ---- O = P V (unnormalized P, fp32 acc; B operand from Vt rows)
    f32x4 oAcc[2][2];
#pragma unroll
    for (int mi = 0; mi < 2; mi++)
#pragma unroll
      for (int ni = 0; ni < 2; ni++) {
        bf16x8 pa = *(const bf16x8*)&Qs[(mi * 16 + m) * 40 + quad * 8];
        bf16x8 vb = *(const bf16x8*)&Ks[(ni * 16 + m) * 40 + quad * 8];
        f32x4 z = {};
        oAcc[mi][ni] = MFMA16(pa, vb, z);
      }
    // ---- Y[b][d][h*32+t] = O[t][d]/rowsum as FP32; 4 t's per lane -> float4
#pragma unroll
    for (int mi = 0; mi < 2; mi++)
#pragma unroll
      for (int ni = 0; ni < 2; ni++) {
        float4 o;
        o.x = oAcc[mi][ni][0] * invs[mi][0];
        o.y = oAcc[mi][ni][1] * invs[mi][1];
        o.z = oAcc[mi][ni][2] * invs[mi][2];
        o.w = oAcc[mi][ni][3] * invs[mi][3];
        int d = ni * 16 + m;
        int t0 = mi * 16 + quad * 4;
        *(float4*)&y[(size_t)b * 16384 + (size_t)d * 512 + h * 32 + t0] = o;
      }
  }
}

// ---------------------------------------------------------------------------
// K2: Out = Y @ Wp^T + bp, in place on d_out (fp32 Y and out, same bytes ->
// each block stages its full 64 rows to LDS before any write). grid = 2048
// (BM=64), block = 256; wave owns 128 cols.
// R2: fragment-packed coalesced Wp loads (g = wave*8+ni); no koff.
// ---------------------------------------------------------------------------
template <bool BF16W>
__global__ __launch_bounds__(256, 2) void proj_k(
    float* __restrict__ y,
    const void* __restrict__ wp,
    const float* __restrict__ bp) {
  __shared__ __align__(16) unsigned short Ys[64 * 512];  // 64 KB bf16, swizzled
  const int tid  = threadIdx.x;
  const int lane = tid & 63;
  const int wave = tid >> 6;
  const int m    = lane & 15;
  const int quad = lane >> 4;
  const size_t rbase = (size_t)blockIdx.x * 64;

  { // stage all 64 fp32 Y rows -> bf16 LDS before any write
    const float* yg = y + rbase * 512;
#pragma unroll
    for (int i = 0; i < 16; i++) {
      int c = tid + 256 * i;          // 4096 chunks
      int row = c >> 6, ch = c & 63;
      float4 lo = *(const float4*)&yg[row * 512 + ch * 8];
      float4 hi = *(const float4*)&yg[row * 512 + ch * 8 + 4];
      *(bf16x8*)&Ys[sw(row, ch)] = cvt8(lo, hi);
    }
  }
  __syncthreads();

  const int nb = wave * 128;
  const size_t wbp = wbase0<BF16W>(nb, lane, m, quad);
  const int kmul = BF16W ? 512 : 32;
  f32x4 acc[4][8] = {};
  bf16x8 aA[4], aB[4], wA[8], wB[8];

#define K2A(S, idx) { \
    const int kx = (idx); \
    _Pragma("unroll") \
    for (int mi = 0; mi < 4; mi++) \
      a##S[mi] = *(const bf16x8*)&Ys[sw(mi * 16 + m, kx * 4 + quad)]; }
#define K2W(S, idx) { \
    const size_t kb = (size_t)(idx) * kmul; \
    _Pragma("unroll") \
    for (int ni = 0; ni < 8; ni++) \
      w##S[ni] = ldw<BF16W>(wp, wbp + (size_t)ni * 8192 + kb); }
#define K2MM(S) { \
    _Pragma("unroll") \
    for (int ni = 0; ni < 8; ni++) \
      _Pragma("unroll") \
      for (int mi = 0; mi < 4; mi++) \
        acc[mi][ni] = MFMA16(a##S[mi], w##S[ni], acc[mi][ni]); }

  K2A(A, 0) K2W(A, 0)
  for (int i = 0; i < 14; i += 2) {
    K2A(B, i + 1) K2W(B, i + 1)
    K2MM(A)
    K2A(A, i + 2) K2W(A, i + 2)
    K2MM(B)
  }
  K2A(B, 15) K2W(B, 15)
  K2MM(A)
  K2MM(B)
#undef K2A
#undef K2W
#undef K2MM

  // epilogue: + bp, fp32 store in place
#pragma unroll
  for (int ni = 0; ni < 8; ni++) {
    const int col = nb + ni * 16 + m;
    const float bias = bp[col];
#pragma unroll
    for (int mi = 0; mi < 4; mi++)
#pragma unroll
      for (int r = 0; r < 4; r++) {
        size_t row = rbase + mi * 16 + quad * 4 + r;
        y[row * 512 + col] = acc[mi][ni][r] + bias;
      }
  }
}

extern "C" void kernel_launch(void* const* d_in, const int* in_sizes, int n_in,
                              void* d_out, int out_size, void* d_ws, size_t ws_size,
                              hipStream_t stream) {
  (void)in_sizes; (void)n_in; (void)out_size;
  const float* x  = (const float*)d_in[0];
  const float* wq = (const float*)d_in[1];
  const float* wk = (const float*)d_in[2];
  const float* wv = (const float*)d_in[3];
  const float* wp = (const float*)d_in[4];
  const float* bp = (const float*)d_in[5];
  float* y = (float*)d_out;

  const size_t WE = 262144;  // elems per weight matrix (16*32*512 == 512*512)
  if (ws_size >= 4 * WE * sizeof(unsigned short)) {
    unsigned short* wb = (unsigned short*)d_ws;
    cvt_weights_k<<<512, 256, 0, stream>>>(wq, wk, wv, wp, wb);
    qkv_attn_k<true><<<4096, 256, 0, stream>>>(x, wb, wb + WE, wb + 2 * WE, y);
    proj_k<true><<<2048, 256, 0, stream>>>(y, wb + 3 * WE, bp);
  } else {  // fallback: fp32 weights, original layout, converted in-loop
    qkv_attn_k<false><<<4096, 256, 0, stream>>>(x, wq, wk, wv, y);
    proj_k<false><<<2048, 256, 0, stream>>>(y, wp, bp);
  }
}

// Round 3
// 1266.534 us; speedup vs baseline: 1.1289x; 1.1289x over previous
//
#include <hip/hip_runtime.h>
#include <stdint.h>

// bf16 MFMA fragment types per cdna_hip_programming.md §3
typedef __attribute__((ext_vector_type(8))) short bf16x8;   // 8 bf16 = 4 VGPRs
typedef __attribute__((ext_vector_type(4))) float f32x4;    // C/D for 16x16x32

#define MFMA16(a, b, c) __builtin_amdgcn_mfma_f32_16x16x32_bf16((a), (b), (c), 0, 0, 0)

__device__ __forceinline__ unsigned short f2bf(float f) {
  unsigned int b = __float_as_uint(f);
  b += 0x7FFFu + ((b >> 16) & 1u);   // RNE
  return (unsigned short)(b >> 16);
}
// pack two float4 -> 8 bf16 (RNE)
__device__ __forceinline__ bf16x8 cvt8(const float4 a, const float4 b) {
  bf16x8 r;
  r[0] = (short)f2bf(a.x); r[1] = (short)f2bf(a.y);
  r[2] = (short)f2bf(a.z); r[3] = (short)f2bf(a.w);
  r[4] = (short)f2bf(b.x); r[5] = (short)f2bf(b.y);
  r[6] = (short)f2bf(b.z); r[7] = (short)f2bf(b.w);
  return r;
}
// weight fragment load: bf16 direct (16B) or fp32 + convert (fallback)
template <bool BF16W>
__device__ __forceinline__ bf16x8 ldw(const void* p, size_t off) {
  if constexpr (BF16W) {
    return *(const bf16x8*)((const unsigned short*)p + off);
  } else {
    const float* f = (const float*)p + off;
    return cvt8(*(const float4*)f, *(const float4*)(f + 4));
  }
}
// XOR-swizzled LDS tile index (pitch 512 elems, chunk = 8 elems = 16B).
__device__ __forceinline__ int sw(int row, int chunk) {
  return row * 512 + ((chunk ^ (row & 7)) << 3);
}

// ---------------------------------------------------------------------------
// K0: convert Wq,Wk,Wv,Wp (fp32, 262144 each) -> bf16 FRAGMENT-PACKED layout.
// Packed chunk index c (8 elems each): bits [14:10]=g, [9:6]=kk, [5:4]=quad,
// [3:0]=m. Content: W[g*16+m][kk*32+quad*8 .. +8].
//   K1 frag (head h, n-tile ni, k-step kx): g = h*2+ni  -> every wave load is
//     base + lane*16B, a fully coalesced 1KB read.
//   K2 frag (wave w, ni, kx): g = w*8+ni  (same formula).
// ---------------------------------------------------------------------------
__global__ void cvt_weights_k(const float* __restrict__ wq,
                              const float* __restrict__ wk,
                              const float* __restrict__ wv,
                              const float* __restrict__ wp,
                              unsigned short* __restrict__ dst) {
  const int seg = blockIdx.x >> 7;   // 0..3
  const int blk = blockIdx.x & 127;
  const float* src = (seg == 0) ? wq : (seg == 1) ? wk : (seg == 2) ? wv : wp;
  unsigned short* d = dst + (size_t)seg * 262144;
  const int c = blk * 256 + threadIdx.x;          // 0..32767
  const int row = ((c >> 10) << 4) + (c & 15);    // g*16 + m
  const int col = ((c >> 6) & 15) * 32 + ((c >> 4) & 3) * 8;  // kk*32 + quad*8
  const float* s = src + row * 512 + col;
  *(bf16x8*)&d[(size_t)c * 8] = cvt8(*(const float4*)s, *(const float4*)(s + 4));
}

// Weight fragment offset: packed (bf16 ws) vs original row-major (fp32 fallback).
// off(ni,kx) = base + ni*8192 + kx*kmul in both cases.
template <bool PACKED>
__device__ __forceinline__ size_t wbase0(int g32, int lane, int m, int quad) {
  if constexpr (PACKED) return (size_t)g32 * 512 + (size_t)lane * 8;
  else                  return (size_t)(g32 + m) * 512 + quad * 8;
}

// ---------------------------------------------------------------------------
// K1: per-batch fused QKV projection + causal attention.
// R3: packed coalesced weights (kept from R2) + LDS back to 63488 B
// (3 scratch buffers -> exactly 2 blocks/CU, de-thrash) + 5-slot / 4-deep
// register pipeline on the weight stream to cover L3-hit latency.
// grid = 4096 (one batch), block = 256 (4 waves; wave w -> head hg*4+w).
// ---------------------------------------------------------------------------
template <bool BF16W>
__global__ __launch_bounds__(256, 2) void qkv_attn_k(
    const float* __restrict__ x,
    const void* __restrict__ wq,
    const void* __restrict__ wk,
    const void* __restrict__ wv,
    float* __restrict__ y) {
  __shared__ __align__(16) unsigned short Xs[32 * 512];       // 32 KB bf16, swizzled
  __shared__ __align__(16) unsigned short Scr[4][3][32 * 40]; // Q/K/Vt scratch, 30 KB
  const int tid  = threadIdx.x;
  const int lane = tid & 63;
  const int wave = tid >> 6;
  const int m    = lane & 15;   // tile row/col within 16
  const int quad = lane >> 4;   // 0..3
  const int b    = blockIdx.x;

  { // stage X[b] (32 x 512 fp32) into LDS as bf16
    const float* xg = x + (size_t)b * (32 * 512);
#pragma unroll
    for (int i = 0; i < 8; i++) {
      int c = tid + 256 * i;          // 2048 chunks of 8 elems
      int row = c >> 6, ch = c & 63;
      float4 lo = *(const float4*)&xg[row * 512 + ch * 8];
      float4 hi = *(const float4*)&xg[row * 512 + ch * 8 + 4];
      *(bf16x8*)&Xs[sw(row, ch)] = cvt8(lo, hi);
    }
  }
  __syncthreads();

  unsigned short* Qs = &Scr[wave][0][0];  // Q, later re-used for P
  unsigned short* Ks = &Scr[wave][1][0];
  unsigned short* Vt = &Scr[wave][2][0];  // V transposed: Vt[d][s]

  for (int hg = 0; hg < 4; hg++) {
    const int h = hg * 4 + wave;
    // ---- GEMM: Q,K,V [32x32] = X[32x512] @ W_h[32x512]^T, fp32 acc
    f32x4 aq[2][2] = {}; f32x4 ak[2][2] = {}; f32x4 av[2][2] = {};
    const size_t wb = wbase0<BF16W>(h * 32, lane, m, quad);
    const int kmul = BF16W ? 512 : 32;

    // 5 weight slots (token-pasted names; no runtime-indexed arrays -> regs)
    bf16x8 q00, q10, k00, k10, v00, v10;
    bf16x8 q01, q11, k01, k11, v01, v11;
    bf16x8 q02, q12, k02, k12, v02, v12;
    bf16x8 q03, q13, k03, k13, v03, v13;
    bf16x8 q04, q14, k04, k14, v04, v14;
    bf16x8 a0A, a1A, a0B, a1B;

#define LDW(n, idx) { const size_t kb = wb + (size_t)(idx) * kmul; \
    q0##n = ldw<BF16W>(wq, kb); q1##n = ldw<BF16W>(wq, kb + 8192); \
    k0##n = ldw<BF16W>(wk, kb); k1##n = ldw<BF16W>(wk, kb + 8192); \
    v0##n = ldw<BF16W>(wv, kb); v1##n = ldw<BF16W>(wv, kb + 8192); }
#define LDA(s, idx) { \
    a0##s = *(const bf16x8*)&Xs[sw(m, (idx) * 4 + quad)]; \
    a1##s = *(const bf16x8*)&Xs[sw(16 + m, (idx) * 4 + quad)]; }
#define MMF(n, s) { \
    aq[0][0] = MFMA16(a0##s, q0##n, aq[0][0]); \
    aq[1][0] = MFMA16(a1##s, q0##n, aq[1][0]); \
    aq[0][1] = MFMA16(a0##s, q1##n, aq[0][1]); \
    aq[1][1] = MFMA16(a1##s, q1##n, aq[1][1]); \
    ak[0][0] = MFMA16(a0##s, k0##n, ak[0][0]); \
    ak[1][0] = MFMA16(a1##s, k0##n, ak[1][0]); \
    ak[0][1] = MFMA16(a0##s, k1##n, ak[0][1]); \
    ak[1][1] = MFMA16(a1##s, k1##n, ak[1][1]); \
    av[0][0] = MFMA16(a0##s, v0##n, av[0][0]); \
    av[1][0] = MFMA16(a1##s, v0##n, av[1][0]); \
    av[0][1] = MFMA16(a0##s, v1##n, av[0][1]); \
    av[1][1] = MFMA16(a1##s, v1##n, av[1][1]); }

    // prologue: 5 weight groups + first A in flight
    LDA(A, 0)
    LDW(0, 0) LDW(1, 1) LDW(2, 2) LDW(3, 3) LDW(4, 4)
    // steady state: compute kx=i (slot i%5, A-parity i%2), prefetch kx=i+5
    LDA(B, 1)  MMF(0, A)  LDW(0, 5)
    LDA(A, 2)  MMF(1, B)  LDW(1, 6)
    LDA(B, 3)  MMF(2, A)  LDW(2, 7)
    LDA(A, 4)  MMF(3, B)  LDW(3, 8)
    LDA(B, 5)  MMF(4, A)  LDW(4, 9)
    LDA(A, 6)  MMF(0, B)  LDW(0, 10)
    LDA(B, 7)  MMF(1, A)  LDW(1, 11)
    LDA(A, 8)  MMF(2, B)  LDW(2, 12)
    LDA(B, 9)  MMF(3, A)  LDW(3, 13)
    LDA(A, 10) MMF(4, B)  LDW(4, 14)
    LDA(B, 11) MMF(0, A)  LDW(0, 15)
    LDA(A, 12) MMF(1, B)
    LDA(B, 13) MMF(2, A)
    LDA(A, 14) MMF(3, B)
    LDA(B, 15) MMF(4, A)
               MMF(0, B)
#undef LDW
#undef LDA
#undef MMF

    // ---- spill Q,K row-major, V transposed (C-layout: row=quad*4+r, col=m)
#pragma unroll
    for (int mi = 0; mi < 2; mi++)
#pragma unroll
      for (int ni = 0; ni < 2; ni++)
#pragma unroll
        for (int r = 0; r < 4; r++) {
          int row = mi * 16 + quad * 4 + r;
          int col = ni * 16 + m;
          Qs[row * 40 + col] = f2bf(aq[mi][ni][r]);
          Ks[row * 40 + col] = f2bf(ak[mi][ni][r]);
          Vt[col * 40 + row] = f2bf(av[mi][ni][r]);
        }
    // ---- S = Q K^T (K-dim = 32 -> single MFMA per 16x16 tile)
    f32x4 sAcc[2][2];
#pragma unroll
    for (int mi = 0; mi < 2; mi++)
#pragma unroll
      for (int ni = 0; ni < 2; ni++) {
        bf16x8 qa = *(const bf16x8*)&Qs[(mi * 16 + m) * 40 + quad * 8];
        bf16x8 kb = *(const bf16x8*)&Ks[(ni * 16 + m) * 40 + quad * 8];
        f32x4 z = {};
        sAcc[mi][ni] = MFMA16(qa, kb, z);
      }
    // ---- causal mask + softmax (row t lives in one 16-lane quad); P -> Qs
    float invs[2][4];
#pragma unroll
    for (int mi = 0; mi < 2; mi++)
#pragma unroll
      for (int r = 0; r < 4; r++) {
        int t = mi * 16 + quad * 4 + r;
        float s0 = sAcc[mi][0][r] * 0.17677669529663687f;  // 1/sqrt(32)
        float s1 = sAcc[mi][1][r] * 0.17677669529663687f;
        s0 = (m <= t) ? s0 : -1e30f;
        s1 = (16 + m <= t) ? s1 : -1e30f;
        float mx = fmaxf(s0, s1);
#pragma unroll
        for (int off = 1; off < 16; off <<= 1) mx = fmaxf(mx, __shfl_xor(mx, off));
        float e0 = __expf(s0 - mx);
        float e1 = __expf(s1 - mx);
        float sm = e0 + e1;
#pragma unroll
        for (int off = 1; off < 16; off <<= 1) sm += __shfl_xor(sm, off);
        invs[mi][r] = 1.0f / sm;           // normalize O after PV (fp32)
        Qs[t * 40 + m] = f2bf(e0);
        Qs[t * 40 + 16 + m] = f2bf(e1);
      }
    // ---- O = P V (unnormalized P, fp32 acc; B operand from Vt rows)
    f32x4 oAcc[2][2];
#pragma unroll
    for (int mi = 0; mi < 2; mi++)
#pragma unroll
      for (int ni = 0; ni < 2; ni++) {
        bf16x8 pa = *(const bf16x8*)&Qs[(mi * 16 + m) * 40 + quad * 8];
        bf16x8 vb = *(const bf16x8*)&Vt[(ni * 16 + m) * 40 + quad * 8];
        f32x4 z = {};
        oAcc[mi][ni] = MFMA16(pa, vb, z);
      }
    // ---- Y[b][d][h*32+t] = O[t][d]/rowsum as FP32; 4 t's per lane -> float4
#pragma unroll
    for (int mi = 0; mi < 2; mi++)
#pragma unroll
      for (int ni = 0; ni < 2; ni++) {
        float4 o;
        o.x = oAcc[mi][ni][0] * invs[mi][0];
        o.y = oAcc[mi][ni][1] * invs[mi][1];
        o.z = oAcc[mi][ni][2] * invs[mi][2];
        o.w = oAcc[mi][ni][3] * invs[mi][3];
        int d = ni * 16 + m;
        int t0 = mi * 16 + quad * 4;
        *(float4*)&y[(size_t)b * 16384 + (size_t)d * 512 + h * 32 + t0] = o;
      }
  }
}

// ---------------------------------------------------------------------------
// K2: Out = Y @ Wp^T + bp, in place on d_out (fp32 Y and out, same bytes ->
// each block stages its full 64 rows to LDS before any write). grid = 2048
// (BM=64), block = 256; wave owns 128 cols. Packed coalesced Wp loads.
// ---------------------------------------------------------------------------
template <bool BF16W>
__global__ __launch_bounds__(256, 2) void proj_k(
    float* __restrict__ y,
    const void* __restrict__ wp,
    const float* __restrict__ bp) {
  __shared__ __align__(16) unsigned short Ys[64 * 512];  // 64 KB bf16, swizzled
  const int tid  = threadIdx.x;
  const int lane = tid & 63;
  const int wave = tid >> 6;
  const int m    = lane & 15;
  const int quad = lane >> 4;
  const size_t rbase = (size_t)blockIdx.x * 64;

  { // stage all 64 fp32 Y rows -> bf16 LDS before any write
    const float* yg = y + rbase * 512;
#pragma unroll
    for (int i = 0; i < 16; i++) {
      int c = tid + 256 * i;          // 4096 chunks
      int row = c >> 6, ch = c & 63;
      float4 lo = *(const float4*)&yg[row * 512 + ch * 8];
      float4 hi = *(const float4*)&yg[row * 512 + ch * 8 + 4];
      *(bf16x8*)&Ys[sw(row, ch)] = cvt8(lo, hi);
    }
  }
  __syncthreads();

  const int nb = wave * 128;
  const size_t wbp = wbase0<BF16W>(nb, lane, m, quad);
  const int kmul = BF16W ? 512 : 32;
  f32x4 acc[4][8] = {};
  bf16x8 aA[4], aB[4], wA[8], wB[8];

#define K2A(S, idx) { \
    const int kx = (idx); \
    _Pragma("unroll") \
    for (int mi = 0; mi < 4; mi++) \
      a##S[mi] = *(const bf16x8*)&Ys[sw(mi * 16 + m, kx * 4 + quad)]; }
#define K2W(S, idx) { \
    const size_t kb = (size_t)(idx) * kmul; \
    _Pragma("unroll") \
    for (int ni = 0; ni < 8; ni++) \
      w##S[ni] = ldw<BF16W>(wp, wbp + (size_t)ni * 8192 + kb); }
#define K2MM(S) { \
    _Pragma("unroll") \
    for (int ni = 0; ni < 8; ni++) \
      _Pragma("unroll") \
      for (int mi = 0; mi < 4; mi++) \
        acc[mi][ni] = MFMA16(a##S[mi], w##S[ni], acc[mi][ni]); }

  K2A(A, 0) K2W(A, 0)
  for (int i = 0; i < 14; i += 2) {
    K2A(B, i + 1) K2W(B, i + 1)
    K2MM(A)
    K2A(A, i + 2) K2W(A, i + 2)
    K2MM(B)
  }
  K2A(B, 15) K2W(B, 15)
  K2MM(A)
  K2MM(B)
#undef K2A
#undef K2W
#undef K2MM

  // epilogue: + bp, fp32 store in place
#pragma unroll
  for (int ni = 0; ni < 8; ni++) {
    const int col = nb + ni * 16 + m;
    const float bias = bp[col];
#pragma unroll
    for (int mi = 0; mi < 4; mi++)
#pragma unroll
      for (int r = 0; r < 4; r++) {
        size_t row = rbase + mi * 16 + quad * 4 + r;
        y[row * 512 + col] = acc[mi][ni][r] + bias;
      }
  }
}

extern "C" void kernel_launch(void* const* d_in, const int* in_sizes, int n_in,
                              void* d_out, int out_size, void* d_ws, size_t ws_size,
                              hipStream_t stream) {
  (void)in_sizes; (void)n_in; (void)out_size;
  const float* x  = (const float*)d_in[0];
  const float* wq = (const float*)d_in[1];
  const float* wk = (const float*)d_in[2];
  const float* wv = (const float*)d_in[3];
  const float* wp = (const float*)d_in[4];
  const float* bp = (const float*)d_in[5];
  float* y = (float*)d_out;

  const size_t WE = 262144;  // elems per weight matrix (16*32*512 == 512*512)
  if (ws_size >= 4 * WE * sizeof(unsigned short)) {
    unsigned short* wb = (unsigned short*)d_ws;
    cvt_weights_k<<<512, 256, 0, stream>>>(wq, wk, wv, wp, wb);
    qkv_attn_k<true><<<4096, 256, 0, stream>>>(x, wb, wb + WE, wb + 2 * WE, y);
    proj_k<true><<<2048, 256, 0, stream>>>(y, wb + 3 * WE, bp);
  } else {  // fallback: fp32 weights, original layout, converted in-loop
    qkv_attn_k<false><<<4096, 256, 0, stream>>>(x, wq, wk, wv, y);
    proj_k<false><<<2048, 256, 0, stream>>>(y, wp, bp);
  }
}